// Round 7
// baseline (441.122 us; speedup 1.0000x reference)
//
#include <hip/hip_runtime.h>
#include <hip/hip_bf16.h>
#include <hip/hip_cooperative_groups.h>

namespace cg = cooperative_groups;

#define H 2
#define C 64
#define IN_CH 64
#define HC 128
#define NEG_SLOPE 0.2f
#define GRID 256
#define BLOCK 1024
#define NWAVE 16  // waves per block

// One cooperative kernel, phases separated by grid.sync():
// P0 zero | P1 proj | P2 bucket-hist | P3a row scan | P3b bucket scan |
// P4 scatter (packed) | P5 per-bucket CSR | P6 aggregate | P7 pool
__global__ __launch_bounds__(BLOCK, 4) void fused_kernel(
    const float* __restrict__ x, const int* __restrict__ edge,
    const int* __restrict__ batch, const float* __restrict__ W,
    const float* __restrict__ att_src, const float* __restrict__ att_dst,
    const float* __restrict__ bias, float* __restrict__ out,
    __hip_bfloat16* __restrict__ xp, float2* __restrict__ asrc,
    float2* __restrict__ adst, int* __restrict__ hist,
    int* __restrict__ rowsum, int* __restrict__ staged,
    int* __restrict__ off, int* __restrict__ csr,
    float* __restrict__ gsum, int* __restrict__ gcnt,
    int N, int E, int G) {
    cg::grid_group grid = cg::this_grid();
    __shared__ __align__(16) char smemRaw[NWAVE * 64 * 16];  // 16 KB, reused per phase
    const int tid = threadIdx.x, bid = blockIdx.x;
    const int lane = tid & 63, wid = tid >> 6;
    const int* srcE = edge;
    const int* dstE = edge + E;
    const int nbuck = (N + 255) >> 8;               // <= 256 (N <= 65536)
    const int chunkE = (E + GRID - 1) / GRID;

    // ---- P0: zero gsum/gcnt ----
    for (int i = bid * BLOCK + tid; i < G * C; i += GRID * BLOCK) gsum[i] = 0.f;
    for (int i = bid * BLOCK + tid; i < G; i += GRID * BLOCK) gcnt[i] = 0;

    // ---- P1: projection + attention dots (8 nodes / block-iter) ----
    {
        float w[64];
        int ch = tid & 127;
        const float4* wr = reinterpret_cast<const float4*>(W + (size_t)ch * IN_CH);
#pragma unroll
        for (int q = 0; q < 16; q++) {
            float4 v = wr[q];
            w[4 * q] = v.x; w[4 * q + 1] = v.y; w[4 * q + 2] = v.z; w[4 * q + 3] = v.w;
        }
        float a_s = att_src[ch], a_d = att_dst[ch];
        int sub = tid >> 7;          // node sub-index 0..7 (wave-uniform)
        int head = (tid >> 6) & 1;
        for (int base = bid * 8; base < N; base += GRID * 8) {
            int n = base + sub;
            if (n < N) {
                const float* xr = x + (size_t)n * IN_CH;  // wave-uniform -> s_load
                float acc = 0.f;
#pragma unroll
                for (int k = 0; k < 64; k++) acc = fmaf(w[k], xr[k], acc);
                xp[(size_t)n * HC + ch] = __float2bfloat16(acc);
                float as = acc * a_s, ad = acc * a_d;
#pragma unroll
                for (int d = 32; d > 0; d >>= 1) {
                    as += __shfl_xor(as, d, 64);
                    ad += __shfl_xor(ad, d, 64);
                }
                if (lane == 0) {
                    ((float*)asrc)[2 * n + head] = as;
                    ((float*)adst)[2 * n + head] = ad;
                }
            }
        }
    }

    // ---- P2: per-block bucket histogram ----
    {
        int* lh = (int*)smemRaw;
        for (int i = tid; i < nbuck; i += BLOCK) lh[i] = 0;
        __syncthreads();
        int beg = bid * chunkE, end = min(beg + chunkE, E);
        for (int i = beg + tid; i < end; i += BLOCK) atomicAdd(&lh[dstE[i] >> 8], 1);
        __syncthreads();
        for (int i = tid; i < nbuck; i += BLOCK) hist[i * GRID + bid] = lh[i];
    }
    grid.sync();

    // ---- P3a: within-row exclusive scan (row = bucket), rowsum = row total ----
    if (bid < nbuck) {
        int* sh = (int*)smemRaw;
        int v = 0;
        if (tid < GRID) { v = hist[bid * GRID + tid]; sh[tid] = v; }
        __syncthreads();
        for (int d = 1; d < GRID; d <<= 1) {
            int u = (tid >= d && tid < GRID) ? sh[tid - d] : 0;
            __syncthreads();
            if (tid < GRID) sh[tid] += u;
            __syncthreads();
        }
        if (tid < GRID) hist[bid * GRID + tid] = sh[tid] - v;
        if (tid == GRID - 1) rowsum[bid] = sh[GRID - 1];
    }
    grid.sync();

    // ---- P3b: exclusive scan of bucket totals (block 0) ----
    if (bid == 0) {
        int* sh = (int*)smemRaw;
        int v = (tid < nbuck) ? rowsum[tid] : 0;
        if (tid < 256) sh[tid] = v;
        __syncthreads();
        for (int d = 1; d < 256; d <<= 1) {
            int u = (tid >= d && tid < 256) ? sh[tid - d] : 0;
            __syncthreads();
            if (tid < 256) sh[tid] += u;
            __syncthreads();
        }
        if (tid < nbuck) rowsum[tid] = sh[tid] - v;
        if (tid == nbuck - 1) rowsum[nbuck] = sh[tid];  // == E
    }
    grid.sync();

    // ---- P4: scatter into bucket-ordered staging, packed src | (dstLocal<<20) ----
    {
        int* cur = (int*)smemRaw;
        for (int i = tid; i < nbuck; i += BLOCK) cur[i] = hist[i * GRID + bid] + rowsum[i];
        __syncthreads();
        int beg = bid * chunkE, end = min(beg + chunkE, E);
        for (int i = beg + tid; i < end; i += BLOCK) {
            int s = srcE[i], d = dstE[i];
            int pos = atomicAdd(&cur[d >> 8], 1);
            staged[pos] = s | ((d & 255) << 20);
        }
    }
    grid.sync();

    // ---- P5: per-bucket CSR finalize ----
    if (bid < nbuck) {
        int* lh = (int*)smemRaw;       // 256
        int* sh = lh + 256;            // 256
        int* cur = sh + 256;           // 256
        int beg = rowsum[bid], end = rowsum[bid + 1];
        if (tid < 256) lh[tid] = 0;
        __syncthreads();
        for (int i = beg + tid; i < end; i += BLOCK) atomicAdd(&lh[staged[i] >> 20], 1);
        __syncthreads();
        int v = (tid < 256) ? lh[tid] : 0;
        if (tid < 256) sh[tid] = v;
        __syncthreads();
        for (int d = 1; d < 256; d <<= 1) {
            int u = (tid >= d && tid < 256) ? sh[tid - d] : 0;
            __syncthreads();
            if (tid < 256) sh[tid] += u;
            __syncthreads();
        }
        if (tid < 256) {
            int ex = sh[tid] - v;
            int nd = bid * 256 + tid;
            if (nd < N) off[nd] = beg + ex;
            if (nd == N - 1) off[N] = end;
            cur[tid] = beg + ex;
        }
        __syncthreads();
        for (int i = beg + tid; i < end; i += BLOCK) {
            int e = staged[i];
            int pos = atomicAdd(&cur[e >> 20], 1);
            csr[pos] = e & 0xFFFFF;
        }
    }
    grid.sync();

    // ---- P6: softmax + aggregation (R6 logic; one wave per node, 16 waves/block) ----
    {
        float4* st = ((float4*)smemRaw) + wid * 64;
        const uint* xpw = reinterpret_cast<const uint*>(xp);
        for (int n0 = bid * NWAVE; n0 < N; n0 += GRID * NWAVE) {
            int n = n0 + wid;
            if (n >= N) continue;
            int o0 = off[n];
            int degE = off[n + 1] - o0;
            float2 ad = adst[n];
            float2 asn = asrc[n];
            float es0 = asn.x + ad.x; es0 = (es0 > 0.f) ? es0 : NEG_SLOPE * es0;
            float es1 = asn.y + ad.y; es1 = (es1 > 0.f) ? es1 : NEG_SLOPE * es1;
            float ws0 = __expf(es0), ws1 = __expf(es1);
            float s0 = (lane == 0) ? ws0 : 0.f;
            float s1 = (lane == 0) ? ws1 : 0.f;
            float accx, accy;
            {
                float wgt = (lane < 32) ? ws0 : ws1;
                uint u = xpw[(size_t)n * 64 + lane];
                accx = wgt * __uint_as_float(u << 16);
                accy = wgt * __uint_as_float(u & 0xffff0000u);
            }
            for (int base = 0; base < degE; base += 64) {
                int i = base + lane;
                int idx = 0;
                float w0 = 0.f, w1 = 0.f;
                if (i < degE) {
                    idx = csr[o0 + i];
                    float2 as2 = asrc[idx];
                    float t0 = as2.x + ad.x; t0 = (t0 > 0.f) ? t0 : NEG_SLOPE * t0;
                    float t1 = as2.y + ad.y; t1 = (t1 > 0.f) ? t1 : NEG_SLOPE * t1;
                    w0 = __expf(t0);
                    w1 = __expf(t1);
                }
                s0 += w0;
                s1 += w1;
                st[lane] = make_float4(__int_as_float(idx), w0, w1, 0.f);
                int cnt = min(degE - base, 64);
                int nb16 = (cnt + 15) >> 4;  // padded slots: w=0, idx=0 (harmless)
                for (int b2 = 0; b2 < nb16; b2++) {
                    float4 e[16];
#pragma unroll
                    for (int j = 0; j < 16; j++) e[j] = st[b2 * 16 + j];
                    uint bu[16];
#pragma unroll
                    for (int j = 0; j < 16; j++) {
                        int s2 = __float_as_int(e[j].x);
                        bu[j] = xpw[(size_t)s2 * 64 + lane];
                    }
#pragma unroll
                    for (int j = 0; j < 16; j++) {
                        float wgt = (lane < 32) ? e[j].y : e[j].z;
                        accx = fmaf(wgt, __uint_as_float(bu[j] << 16), accx);
                        accy = fmaf(wgt, __uint_as_float(bu[j] & 0xffff0000u), accy);
                    }
                }
            }
#pragma unroll
            for (int d = 32; d > 0; d >>= 1) {
                s0 += __shfl_xor(s0, d, 64);
                s1 += __shfl_xor(s1, d, 64);
            }
            float inv = (lane < 32) ? (1.f / s0) : (1.f / s1);
            accx *= inv;
            accy *= inv;
            float ox = 0.5f * (accx + __shfl_xor(accx, 32, 64));
            float oy = 0.5f * (accy + __shfl_xor(accy, 32, 64));
            int g = batch[n];
            if (lane < 32) {
                float vx = ox + bias[2 * lane];
                float vy = oy + bias[2 * lane + 1];
                *reinterpret_cast<float2*>(out + (size_t)n * C + 2 * lane) = make_float2(vx, vy);
                atomicAdd(&gsum[(size_t)g * C + 2 * lane], vx);
                atomicAdd(&gsum[(size_t)g * C + 2 * lane + 1], vy);
            }
            if (lane == 0) atomicAdd(&gcnt[g], 1);
        }
    }
    grid.sync();

    // ---- P7: pool finalize ----
    for (int i = bid * BLOCK + tid; i < G * C; i += GRID * BLOCK) {
        int g = i >> 6;
        out[(size_t)N * C + i] = gsum[i] / fmaxf((float)gcnt[g], 1.f);
    }
}

extern "C" void kernel_launch(void* const* d_in, const int* in_sizes, int n_in,
                              void* d_out, int out_size, void* d_ws, size_t ws_size,
                              hipStream_t stream) {
    const float* x       = (const float*)d_in[0];
    const int*   edge    = (const int*)d_in[1];
    const int*   batch   = (const int*)d_in[2];
    const float* W       = (const float*)d_in[3];
    const float* att_src = (const float*)d_in[4];
    const float* att_dst = (const float*)d_in[5];
    const float* bias    = (const float*)d_in[6];
    float* out = (float*)d_out;

    int N = in_sizes[0] / IN_CH;
    int E = in_sizes[1] / 2;
    int G = out_size / C - N;
    int nbuck = (N + 255) >> 8;

    char* p = (char*)d_ws;
    auto alloc = [&](size_t bytes) {
        char* r = p;
        p += (bytes + 255) & ~(size_t)255;
        return r;
    };
    __hip_bfloat16* xp = (__hip_bfloat16*)alloc((size_t)N * HC * 2);
    float2* asrc   = (float2*)alloc((size_t)N * 8);
    float2* adst   = (float2*)alloc((size_t)N * 8);
    int*    hist   = (int*)alloc((size_t)nbuck * GRID * 4);
    int*    rowsum = (int*)alloc((size_t)(nbuck + 1) * 4);
    int*    staged = (int*)alloc((size_t)E * 4);
    int*    off    = (int*)alloc((size_t)(N + 1) * 4);
    int*    csr    = (int*)alloc((size_t)E * 4);
    float*  gsum   = (float*)alloc((size_t)G * C * 4);
    int*    gcnt   = (int*)alloc((size_t)G * 4);

    void* params[] = {
        (void*)&x, (void*)&edge, (void*)&batch, (void*)&W, (void*)&att_src,
        (void*)&att_dst, (void*)&bias, (void*)&out, (void*)&xp, (void*)&asrc,
        (void*)&adst, (void*)&hist, (void*)&rowsum, (void*)&staged, (void*)&off,
        (void*)&csr, (void*)&gsum, (void*)&gcnt, (void*)&N, (void*)&E, (void*)&G
    };
    hipLaunchCooperativeKernel((const void*)fused_kernel, dim3(GRID), dim3(BLOCK),
                               params, 0, stream);
}

// Round 8
// 235.748 us; speedup vs baseline: 1.8712x; 1.8712x over previous
//
#include <hip/hip_runtime.h>
#include <hip/hip_bf16.h>

#define H 2
#define C 64
#define IN_CH 64
#define HC (H*C)
#define NEG_SLOPE 0.2f
#define NBUCK_MAX 256
#define NBLK 1024   // blocks for hist/scatter passes (16 waves/CU)

// ---------------- Kernel A: projection + attention dots ----------------
__global__ __launch_bounds__(128) void proj_kernel(
    const float* __restrict__ x, const float* __restrict__ W,
    const float* __restrict__ att_src, const float* __restrict__ att_dst,
    __hip_bfloat16* __restrict__ xp, float* __restrict__ asrc,
    float* __restrict__ adst, int N) {
    int t = threadIdx.x;  // output channel 0..127
    float w[64];
    const float4* wr = reinterpret_cast<const float4*>(W + (size_t)t * IN_CH);
#pragma unroll
    for (int q = 0; q < 16; q++) {
        float4 v = wr[q];
        w[4 * q] = v.x; w[4 * q + 1] = v.y; w[4 * q + 2] = v.z; w[4 * q + 3] = v.w;
    }
    float a_s = att_src[t], a_d = att_dst[t];
    int lane = t & 63, head = t >> 6;
    for (int n = blockIdx.x; n < N; n += gridDim.x) {
        const float* xr = x + (size_t)n * IN_CH;  // wave-uniform address
        float acc = 0.f;
#pragma unroll
        for (int k = 0; k < 64; k++) acc = fmaf(w[k], xr[k], acc);
        xp[(size_t)n * HC + t] = __float2bfloat16(acc);
        float as = acc * a_s, ad = acc * a_d;
#pragma unroll
        for (int d = 32; d > 0; d >>= 1) {
            as += __shfl_xor(as, d, 64);
            ad += __shfl_xor(ad, d, 64);
        }
        if (lane == 0) {
            asrc[(size_t)n * H + head] = as;
            adst[(size_t)n * H + head] = ad;
        }
    }
}

// ---------------- Sort pass 1: per-block bucket histogram (NBLK blocks) ----------------
__global__ __launch_bounds__(256) void hist_kernel(const int* __restrict__ dstE,
                                                   int* __restrict__ hist,
                                                   int E, int nbuck, int chunkE) {
    __shared__ int lh[NBUCK_MAX];
    for (int t = threadIdx.x; t < nbuck; t += 256) lh[t] = 0;
    __syncthreads();
    int beg = blockIdx.x * chunkE;
    int end = min(beg + chunkE, E);
    for (int i = beg + threadIdx.x; i < end; i += 256)
        atomicAdd(&lh[dstE[i] >> 8], 1);
    __syncthreads();
    for (int t = threadIdx.x; t < nbuck; t += 256)
        hist[t * NBLK + blockIdx.x] = lh[t];  // bucket-major rows of length NBLK
}

// ---------------- Sort pass 2a: per-bucket row scan (nbuck blocks, 256 thr) --------
// exclusive-scan each row of NBLK counts in LDS; rowsum[b] = row total
__global__ __launch_bounds__(256) void scan_rows_kernel(int* __restrict__ hist,
                                                        int* __restrict__ rowsum) {
    int b = blockIdx.x, t = threadIdx.x;
    int* row = hist + b * NBLK;
    int v[4];
    int s = 0;
#pragma unroll
    for (int j = 0; j < 4; j++) { v[j] = row[t * 4 + j]; s += v[j]; }
    __shared__ int sh[256];
    sh[t] = s;
    __syncthreads();
    for (int d = 1; d < 256; d <<= 1) {
        int u = (t >= d) ? sh[t - d] : 0;
        __syncthreads();
        sh[t] += u;
        __syncthreads();
    }
    int run = sh[t] - s;
#pragma unroll
    for (int j = 0; j < 4; j++) { row[t * 4 + j] = run; run += v[j]; }
    if (t == 255) rowsum[b] = sh[255];
}

// ---------------- Sort pass 2b: scan of bucket totals (1 block) ----------------
__global__ __launch_bounds__(256) void scan_base_kernel(int* __restrict__ rowsum,
                                                        int* __restrict__ bucketBase,
                                                        int nbuck) {
    int t = threadIdx.x;
    int v = (t < nbuck) ? rowsum[t] : 0;
    __shared__ int sh[256];
    sh[t] = v;
    __syncthreads();
    for (int d = 1; d < 256; d <<= 1) {
        int u = (t >= d) ? sh[t - d] : 0;
        __syncthreads();
        sh[t] += u;
        __syncthreads();
    }
    if (t < nbuck) bucketBase[t] = sh[t] - v;
    if (t == nbuck - 1) bucketBase[nbuck] = sh[t];  // == E
}

// ---------------- Sort pass 3: scatter into bucket-ordered staging (packed) ----------
__global__ __launch_bounds__(256) void bucket_scatter_kernel(
    const int* __restrict__ srcE, const int* __restrict__ dstE,
    const int* __restrict__ hist, const int* __restrict__ bucketBase,
    int* __restrict__ staged, int E, int nbuck, int chunkE) {
    __shared__ int cur[NBUCK_MAX];
    for (int t = threadIdx.x; t < nbuck; t += 256)
        cur[t] = hist[t * NBLK + blockIdx.x] + bucketBase[t];
    __syncthreads();
    int beg = blockIdx.x * chunkE;
    int end = min(beg + chunkE, E);
    for (int i = beg + threadIdx.x; i < end; i += 256) {
        int s = srcE[i], d = dstE[i];
        int pos = atomicAdd(&cur[d >> 8], 1);
        staged[pos] = s | ((d & 255) << 20);  // src in [0,2^20), local dst in 8 bits
    }
}

// ---------------- Sort pass 4: per-bucket CSR finalize (512 thr) ----------------
__global__ __launch_bounds__(512) void bucket_csr_kernel(
    const int* __restrict__ staged, const int* __restrict__ bucketBase,
    int* __restrict__ off, int* __restrict__ csr, int N) {
    int b = blockIdx.x, t = threadIdx.x;
    int beg = bucketBase[b], end = bucketBase[b + 1];
    __shared__ int lh[256], sh[256], cur[256];
    if (t < 256) lh[t] = 0;
    __syncthreads();
    for (int i = beg + t; i < end; i += 512)
        atomicAdd(&lh[staged[i] >> 20], 1);
    __syncthreads();
    int v = (t < 256) ? lh[t] : 0;
    if (t < 256) sh[t] = v;
    __syncthreads();
    for (int d = 1; d < 256; d <<= 1) {
        int u = (t >= d && t < 256) ? sh[t - d] : 0;
        __syncthreads();
        if (t < 256) sh[t] += u;
        __syncthreads();
    }
    if (t < 256) {
        int ex = sh[t] - v;
        int nd = b * 256 + t;
        if (nd < N) off[nd] = beg + ex;
        if (nd == N - 1) off[N] = end;
        cur[t] = beg + ex;
    }
    __syncthreads();
    for (int i = beg + t; i < end; i += 512) {
        int e = staged[i];
        int pos = atomicAdd(&cur[e >> 20], 1);
        csr[pos] = e & 0xFFFFF;
    }
}

// ---------------- Kernel E: softmax + aggregation, one wave per dst node ----------------
__global__ __launch_bounds__(256) void aggregate_kernel(
    const __hip_bfloat16* __restrict__ xp, const float2* __restrict__ asrc,
    const float2* __restrict__ adst, const int* __restrict__ off,
    const int* __restrict__ csr, const float* __restrict__ bias,
    const int* __restrict__ batch, float* __restrict__ out,
    float* __restrict__ gsum, int* __restrict__ gcnt, int N) {
    __shared__ float4 stage[4][64];
    int wid = threadIdx.x >> 6;
    int n = blockIdx.x * 4 + wid;
    if (n >= N) return;
    int lane = threadIdx.x & 63;
    float4* st = stage[wid];
    int o0 = off[n];
    int degE = off[n + 1] - o0;  // real edges only (self-loop analytic)
    float2 ad = adst[n];
    float2 asn = asrc[n];
    float es0 = asn.x + ad.x; es0 = (es0 > 0.f) ? es0 : NEG_SLOPE * es0;
    float es1 = asn.y + ad.y; es1 = (es1 > 0.f) ? es1 : NEG_SLOPE * es1;
    float ws0 = __expf(es0), ws1 = __expf(es1);
    // self-loop weight must enter the lane-reduced denominator exactly ONCE:
    float s0 = (lane == 0) ? ws0 : 0.f;
    float s1 = (lane == 0) ? ws1 : 0.f;

    const uint* xpw = reinterpret_cast<const uint*>(xp);
    float accx, accy;
    {   // self-loop contribution
        float wgt = (lane < 32) ? ws0 : ws1;
        uint u = xpw[(size_t)n * 64 + lane];
        accx = wgt * __uint_as_float(u << 16);
        accy = wgt * __uint_as_float(u & 0xffff0000u);
    }

    for (int base = 0; base < degE; base += 64) {
        int i = base + lane;
        int idx = 0;
        float w0 = 0.f, w1 = 0.f;
        if (i < degE) {
            idx = csr[o0 + i];
            float2 as = asrc[idx];
            float t0 = as.x + ad.x; t0 = (t0 > 0.f) ? t0 : NEG_SLOPE * t0;
            float t1 = as.y + ad.y; t1 = (t1 > 0.f) ? t1 : NEG_SLOPE * t1;
            w0 = __expf(t0);
            w1 = __expf(t1);
        }
        s0 += w0;
        s1 += w1;
        st[lane] = make_float4(__int_as_float(idx), w0, w1, 0.f);
        int cnt = min(degE - base, 64);
        int nb16 = (cnt + 15) >> 4;  // padded slots carry w=0, idx=0 (harmless)
        for (int b = 0; b < nb16; b++) {
            float4 e[16];
#pragma unroll
            for (int j = 0; j < 16; j++) e[j] = st[b * 16 + j];
            uint bu[16];
#pragma unroll
            for (int j = 0; j < 16; j++) {
                int s2 = __float_as_int(e[j].x);
                bu[j] = xpw[(size_t)s2 * 64 + lane];
            }
#pragma unroll
            for (int j = 0; j < 16; j++) {
                float wgt = (lane < 32) ? e[j].y : e[j].z;
                accx = fmaf(wgt, __uint_as_float(bu[j] << 16), accx);
                accy = fmaf(wgt, __uint_as_float(bu[j] & 0xffff0000u), accy);
            }
        }
    }
#pragma unroll
    for (int d = 32; d > 0; d >>= 1) {
        s0 += __shfl_xor(s0, d, 64);
        s1 += __shfl_xor(s1, d, 64);
    }
    float inv = (lane < 32) ? (1.f / s0) : (1.f / s1);
    accx *= inv;
    accy *= inv;
    float ox = 0.5f * (accx + __shfl_xor(accx, 32, 64));
    float oy = 0.5f * (accy + __shfl_xor(accy, 32, 64));
    int g = batch[n];
    if (lane < 32) {
        float vx = ox + bias[2 * lane];
        float vy = oy + bias[2 * lane + 1];
        *reinterpret_cast<float2*>(out + (size_t)n * C + 2 * lane) = make_float2(vx, vy);
        atomicAdd(&gsum[(size_t)g * C + 2 * lane], vx);
        atomicAdd(&gsum[(size_t)g * C + 2 * lane + 1], vy);
    }
    if (lane == 0) atomicAdd(&gcnt[g], 1);
}

// ---------------- Kernel F: pool finalize ----------------
__global__ void pool_kernel(const float* __restrict__ gsum, const int* __restrict__ gcnt,
                            float* __restrict__ out, int G, int baseOff) {
    int i = blockIdx.x * blockDim.x + threadIdx.x;
    if (i >= G * C) return;
    int g = i >> 6;
    float cnt = (float)max(gcnt[g], 1);
    out[baseOff + i] = gsum[i] / cnt;
}

extern "C" void kernel_launch(void* const* d_in, const int* in_sizes, int n_in,
                              void* d_out, int out_size, void* d_ws, size_t ws_size,
                              hipStream_t stream) {
    const float* x       = (const float*)d_in[0];
    const int*   edge    = (const int*)d_in[1];
    const int*   batch   = (const int*)d_in[2];
    const float* W       = (const float*)d_in[3];
    const float* att_src = (const float*)d_in[4];
    const float* att_dst = (const float*)d_in[5];
    const float* bias    = (const float*)d_in[6];

    int N = in_sizes[0] / IN_CH;
    int E = in_sizes[1] / 2;
    int G = out_size / C - N;
    int nbuck = (N + 255) >> 8;            // 196 for N=50000 (must be <= 256)
    int chunkE = (E + NBLK - 1) / NBLK;

    char* p = (char*)d_ws;
    auto alloc = [&](size_t bytes) {
        char* r = p;
        p += (bytes + 255) & ~(size_t)255;
        return r;
    };
    __hip_bfloat16* xp = (__hip_bfloat16*)alloc((size_t)N * HC * 2);
    float* asrc    = (float*)alloc((size_t)N * H * 4);
    float* adst    = (float*)alloc((size_t)N * H * 4);
    int*   hist    = (int*)alloc((size_t)nbuck * NBLK * 4);
    int*   rowsum  = (int*)alloc((size_t)(nbuck + 1) * 4);
    int*   bucketBase = (int*)alloc((size_t)(nbuck + 1) * 4);
    int*   off     = (int*)alloc((size_t)(N + 1) * 4);
    int*   staged  = (int*)alloc((size_t)E * 4);
    int*   csr     = (int*)alloc((size_t)E * 4);
    float* gsum    = (float*)alloc((size_t)G * C * 4);
    int*   gcnt    = (int*)alloc((size_t)G * 4);

    hipMemsetAsync(gsum, 0, (size_t)G * C * 4, stream);
    hipMemsetAsync(gcnt, 0, (size_t)G * 4, stream);

    const int* srcE = edge;
    const int* dstE = edge + E;

    proj_kernel<<<2048, 128, 0, stream>>>(x, W, att_src, att_dst, xp, asrc, adst, N);
    hist_kernel<<<NBLK, 256, 0, stream>>>(dstE, hist, E, nbuck, chunkE);
    scan_rows_kernel<<<nbuck, 256, 0, stream>>>(hist, rowsum);
    scan_base_kernel<<<1, 256, 0, stream>>>(rowsum, bucketBase, nbuck);
    bucket_scatter_kernel<<<NBLK, 256, 0, stream>>>(srcE, dstE, hist, bucketBase,
                                                    staged, E, nbuck, chunkE);
    bucket_csr_kernel<<<nbuck, 512, 0, stream>>>(staged, bucketBase, off, csr, N);
    aggregate_kernel<<<(N + 3) / 4, 256, 0, stream>>>(xp, (const float2*)asrc, (const float2*)adst,
                                                      off, csr, bias, batch,
                                                      (float*)d_out, gsum, gcnt, N);
    pool_kernel<<<(G * C + 255) / 256, 256, 0, stream>>>(gsum, gcnt, (float*)d_out, G, N * C);
}

// Round 9
// 226.505 us; speedup vs baseline: 1.9475x; 1.0408x over previous
//
#include <hip/hip_runtime.h>
#include <hip/hip_bf16.h>

#define H 2
#define C 64
#define IN_CH 64
#define HC (H*C)
#define NEG_SLOPE 0.2f
#define NBUCK_MAX 256
#define NBLK 1024   // blocks for hist/scatter passes (16 waves/CU)

// ---------------- Kernel A: projection + attention dots ----------------
__global__ __launch_bounds__(128) void proj_kernel(
    const float* __restrict__ x, const float* __restrict__ W,
    const float* __restrict__ att_src, const float* __restrict__ att_dst,
    __hip_bfloat16* __restrict__ xp, float* __restrict__ asrc,
    float* __restrict__ adst, int N) {
    int t = threadIdx.x;  // output channel 0..127
    float w[64];
    const float4* wr = reinterpret_cast<const float4*>(W + (size_t)t * IN_CH);
#pragma unroll
    for (int q = 0; q < 16; q++) {
        float4 v = wr[q];
        w[4 * q] = v.x; w[4 * q + 1] = v.y; w[4 * q + 2] = v.z; w[4 * q + 3] = v.w;
    }
    float a_s = att_src[t], a_d = att_dst[t];
    int lane = t & 63, head = t >> 6;
    for (int n = blockIdx.x; n < N; n += gridDim.x) {
        const float* xr = x + (size_t)n * IN_CH;  // wave-uniform address
        float acc = 0.f;
#pragma unroll
        for (int k = 0; k < 64; k++) acc = fmaf(w[k], xr[k], acc);
        xp[(size_t)n * HC + t] = __float2bfloat16(acc);
        float as = acc * a_s, ad = acc * a_d;
#pragma unroll
        for (int d = 32; d > 0; d >>= 1) {
            as += __shfl_xor(as, d, 64);
            ad += __shfl_xor(ad, d, 64);
        }
        if (lane == 0) {
            asrc[(size_t)n * H + head] = as;
            adst[(size_t)n * H + head] = ad;
        }
    }
}

// ---------------- Sort pass 1: per-block bucket histogram (NBLK blocks) ----------------
__global__ __launch_bounds__(256) void hist_kernel(const int* __restrict__ dstE,
                                                   int* __restrict__ hist,
                                                   int E, int nbuck, int chunkE) {
    __shared__ int lh[NBUCK_MAX];
    for (int t = threadIdx.x; t < nbuck; t += 256) lh[t] = 0;
    __syncthreads();
    int beg = blockIdx.x * chunkE;
    int end = min(beg + chunkE, E);
    for (int i = beg + threadIdx.x; i < end; i += 256)
        atomicAdd(&lh[dstE[i] >> 8], 1);
    __syncthreads();
    for (int t = threadIdx.x; t < nbuck; t += 256)
        hist[t * NBLK + blockIdx.x] = lh[t];  // bucket-major rows of length NBLK
}

// ---------------- Sort pass 2: per-bucket row scan (nbuck blocks, 256 thr) --------
__global__ __launch_bounds__(256) void scan_rows_kernel(int* __restrict__ hist,
                                                        int* __restrict__ rowsum) {
    int b = blockIdx.x, t = threadIdx.x;
    int* row = hist + b * NBLK;
    int v[4];
    int s = 0;
#pragma unroll
    for (int j = 0; j < 4; j++) { v[j] = row[t * 4 + j]; s += v[j]; }
    __shared__ int sh[256];
    sh[t] = s;
    __syncthreads();
    for (int d = 1; d < 256; d <<= 1) {
        int u = (t >= d) ? sh[t - d] : 0;
        __syncthreads();
        sh[t] += u;
        __syncthreads();
    }
    int run = sh[t] - s;
#pragma unroll
    for (int j = 0; j < 4; j++) { row[t * 4 + j] = run; run += v[j]; }
    if (t == 255) rowsum[b] = sh[255];
}

// in-block exclusive scan of rowsum[nbuck] -> bse[], also keeps rs[] copy
__device__ __forceinline__ void base_scan(const int* rowsum, int nbuck,
                                          int* bse, int* rs, int t) {
    int v = (t < nbuck) ? rowsum[t] : 0;
    if (t < 256) { bse[t] = v; rs[t] = v; }
    __syncthreads();
    for (int d = 1; d < 256; d <<= 1) {
        int u = (t >= d && t < 256) ? bse[t - d] : 0;
        __syncthreads();
        if (t < 256) bse[t] += u;
        __syncthreads();
    }
    if (t < 256) bse[t] -= rs[t];  // exclusive
    __syncthreads();
}

// ---------------- Sort pass 3: scatter into bucket-ordered staging (packed) ----------
__global__ __launch_bounds__(256) void bucket_scatter_kernel(
    const int* __restrict__ srcE, const int* __restrict__ dstE,
    const int* __restrict__ hist, const int* __restrict__ rowsum,
    int* __restrict__ staged, int E, int nbuck, int chunkE) {
    __shared__ int bse[256], rs[256], cur[NBUCK_MAX];
    int t = threadIdx.x;
    base_scan(rowsum, nbuck, bse, rs, t);
    for (int i = t; i < nbuck; i += 256)
        cur[i] = hist[i * NBLK + blockIdx.x] + bse[i];
    __syncthreads();
    int beg = blockIdx.x * chunkE;
    int end = min(beg + chunkE, E);
    for (int i = beg + t; i < end; i += 256) {
        int s = srcE[i], d = dstE[i];
        int pos = atomicAdd(&cur[d >> 8], 1);
        staged[pos] = s | ((d & 255) << 20);  // src < 2^20, local dst in bits 20..27
    }
}

// ---------------- Sort pass 4: per-bucket CSR finalize (512 thr) ----------------
__global__ __launch_bounds__(512) void bucket_csr_kernel(
    const int* __restrict__ staged, const int* __restrict__ rowsum,
    int* __restrict__ off, int* __restrict__ csr, int N, int nbuck, int E) {
    int b = blockIdx.x, t = threadIdx.x;
    __shared__ int bse[256], rs[256], lh[256], sh[256], cur[256];
    base_scan(rowsum, nbuck, bse, rs, t);
    int beg = bse[b], end = beg + rs[b];
    if (t < 256) lh[t] = 0;
    __syncthreads();
    for (int i = beg + t; i < end; i += 512)
        atomicAdd(&lh[staged[i] >> 20], 1);
    __syncthreads();
    int v = (t < 256) ? lh[t] : 0;
    if (t < 256) sh[t] = v;
    __syncthreads();
    for (int d = 1; d < 256; d <<= 1) {
        int u = (t >= d && t < 256) ? sh[t - d] : 0;
        __syncthreads();
        if (t < 256) sh[t] += u;
        __syncthreads();
    }
    if (t < 256) {
        int ex = sh[t] - v;
        int nd = b * 256 + t;
        if (nd < N) off[nd] = beg + ex;
        if (nd == N - 1) off[N] = end;
        cur[t] = beg + ex;
    }
    __syncthreads();
    for (int i = beg + t; i < end; i += 512) {
        int e = staged[i];
        int pos = atomicAdd(&cur[e >> 20], 1);
        csr[pos] = e & 0xFFFFF;
    }
}

// -------- gather+FMA over NB16*16 staged edges, all loads issued before FMAs --------
template<int NB16>
__device__ __forceinline__ void gather_fma(const uint* __restrict__ xpw,
                                           const int* __restrict__ sidx,
                                           const float2* __restrict__ swt,
                                           int lane, float& accx, float& accy) {
    uint bu[NB16 * 16];
#pragma unroll
    for (int j = 0; j < NB16 * 16; j++) {
        int s2 = sidx[j];
        bu[j] = xpw[(size_t)s2 * 64 + lane];
    }
#pragma unroll
    for (int j = 0; j < NB16 * 16; j++) {
        float2 wv = swt[j];
        float wgt = (lane < 32) ? wv.x : wv.y;
        accx = fmaf(wgt, __uint_as_float(bu[j] << 16), accx);
        accy = fmaf(wgt, __uint_as_float(bu[j] & 0xffff0000u), accy);
    }
}

// ---------------- Kernel E: softmax + aggregation, one wave per dst node ----------------
__global__ __launch_bounds__(256, 4) void aggregate_kernel(
    const __hip_bfloat16* __restrict__ xp, const float2* __restrict__ asrc,
    const float2* __restrict__ adst, const int* __restrict__ off,
    const int* __restrict__ csr, const float* __restrict__ bias,
    float* __restrict__ out, int N) {
    __shared__ int sidx[4][64];
    __shared__ float2 swt[4][64];
    int wid = threadIdx.x >> 6;
    int n = blockIdx.x * 4 + wid;
    if (n >= N) return;
    int lane = threadIdx.x & 63;
    int* si = sidx[wid];
    float2* sw = swt[wid];
    int o0 = off[n];
    int degE = off[n + 1] - o0;  // real edges only (self-loop analytic)
    float2 ad = adst[n];
    float2 asn = asrc[n];
    float es0 = asn.x + ad.x; es0 = (es0 > 0.f) ? es0 : NEG_SLOPE * es0;
    float es1 = asn.y + ad.y; es1 = (es1 > 0.f) ? es1 : NEG_SLOPE * es1;
    float ws0 = __expf(es0), ws1 = __expf(es1);
    // self-loop weight enters the lane-reduced denominator exactly ONCE:
    float s0 = (lane == 0) ? ws0 : 0.f;
    float s1 = (lane == 0) ? ws1 : 0.f;

    const uint* xpw = reinterpret_cast<const uint*>(xp);
    float accx, accy;
    {   // self-loop contribution
        float wgt = (lane < 32) ? ws0 : ws1;
        uint u = xpw[(size_t)n * 64 + lane];
        accx = wgt * __uint_as_float(u << 16);
        accy = wgt * __uint_as_float(u & 0xffff0000u);
    }

    for (int base = 0; base < degE; base += 64) {
        int i = base + lane;
        int idx = 0;
        float w0 = 0.f, w1 = 0.f;
        if (i < degE) {
            idx = csr[o0 + i];
            float2 as = asrc[idx];
            float t0 = as.x + ad.x; t0 = (t0 > 0.f) ? t0 : NEG_SLOPE * t0;
            float t1 = as.y + ad.y; t1 = (t1 > 0.f) ? t1 : NEG_SLOPE * t1;
            w0 = __expf(t0);
            w1 = __expf(t1);
        }
        s0 += w0;
        s1 += w1;
        si[lane] = idx;
        sw[lane] = make_float2(w0, w1);
        int cnt = min(degE - base, 64);
        int nb16 = (cnt + 15) >> 4;  // padded slots carry w=0, idx=0 (harmless)
        switch (nb16) {
            case 1: gather_fma<1>(xpw, si, sw, lane, accx, accy); break;
            case 2: gather_fma<2>(xpw, si, sw, lane, accx, accy); break;
            case 3: gather_fma<3>(xpw, si, sw, lane, accx, accy); break;
            default: gather_fma<4>(xpw, si, sw, lane, accx, accy); break;
        }
    }
#pragma unroll
    for (int d = 32; d > 0; d >>= 1) {
        s0 += __shfl_xor(s0, d, 64);
        s1 += __shfl_xor(s1, d, 64);
    }
    float inv = (lane < 32) ? (1.f / s0) : (1.f / s1);
    accx *= inv;
    accy *= inv;
    float ox = 0.5f * (accx + __shfl_xor(accx, 32, 64));
    float oy = 0.5f * (accy + __shfl_xor(accy, 32, 64));
    if (lane < 32) {
        float vx = ox + bias[2 * lane];
        float vy = oy + bias[2 * lane + 1];
        *reinterpret_cast<float2*>(out + (size_t)n * C + 2 * lane) = make_float2(vx, vy);
    }
}

// ---------------- Kernel F: pool = segment mean over sorted batch ----------------
// one wave per graph; binary search the contiguous node range of graph g
__global__ __launch_bounds__(64) void pool_kernel(const float* __restrict__ hn,
                                                  const int* __restrict__ batch,
                                                  float* __restrict__ outG, int N, int G) {
    int g = blockIdx.x;
    int c = threadIdx.x;  // 0..63
    int lo = 0, hi = N;
    while (lo < hi) { int mid = (lo + hi) >> 1; if (batch[mid] < g) lo = mid + 1; else hi = mid; }
    int beg = lo;
    lo = beg; hi = N;
    while (lo < hi) { int mid = (lo + hi) >> 1; if (batch[mid] < g + 1) lo = mid + 1; else hi = mid; }
    int end = lo;
    float s = 0.f;
    for (int n = beg; n < end; n++) s += hn[(size_t)n * C + c];
    outG[(size_t)g * C + c] = s / fmaxf((float)(end - beg), 1.f);
}

extern "C" void kernel_launch(void* const* d_in, const int* in_sizes, int n_in,
                              void* d_out, int out_size, void* d_ws, size_t ws_size,
                              hipStream_t stream) {
    const float* x       = (const float*)d_in[0];
    const int*   edge    = (const int*)d_in[1];
    const int*   batch   = (const int*)d_in[2];
    const float* W       = (const float*)d_in[3];
    const float* att_src = (const float*)d_in[4];
    const float* att_dst = (const float*)d_in[5];
    const float* bias    = (const float*)d_in[6];

    int N = in_sizes[0] / IN_CH;
    int E = in_sizes[1] / 2;
    int G = out_size / C - N;
    int nbuck = (N + 255) >> 8;            // 196 for N=50000 (must be <= 256)
    int chunkE = (E + NBLK - 1) / NBLK;

    char* p = (char*)d_ws;
    auto alloc = [&](size_t bytes) {
        char* r = p;
        p += (bytes + 255) & ~(size_t)255;
        return r;
    };
    __hip_bfloat16* xp = (__hip_bfloat16*)alloc((size_t)N * HC * 2);
    float* asrc    = (float*)alloc((size_t)N * H * 4);
    float* adst    = (float*)alloc((size_t)N * H * 4);
    int*   hist    = (int*)alloc((size_t)nbuck * NBLK * 4);
    int*   rowsum  = (int*)alloc((size_t)(nbuck + 1) * 4);
    int*   off     = (int*)alloc((size_t)(N + 1) * 4);
    int*   staged  = (int*)alloc((size_t)E * 4);
    int*   csr     = (int*)alloc((size_t)E * 4);

    const int* srcE = edge;
    const int* dstE = edge + E;

    proj_kernel<<<2048, 128, 0, stream>>>(x, W, att_src, att_dst, xp, asrc, adst, N);
    hist_kernel<<<NBLK, 256, 0, stream>>>(dstE, hist, E, nbuck, chunkE);
    scan_rows_kernel<<<nbuck, 256, 0, stream>>>(hist, rowsum);
    bucket_scatter_kernel<<<NBLK, 256, 0, stream>>>(srcE, dstE, hist, rowsum,
                                                    staged, E, nbuck, chunkE);
    bucket_csr_kernel<<<nbuck, 512, 0, stream>>>(staged, rowsum, off, csr, N, nbuck, E);
    aggregate_kernel<<<(N + 3) / 4, 256, 0, stream>>>(xp, (const float2*)asrc, (const float2*)adst,
                                                      off, csr, bias, (float*)d_out, N);
    pool_kernel<<<G, 64, 0, stream>>>((const float*)d_out, batch, (float*)d_out + (size_t)N * C,
                                      N, G);
}